// Round 1
// baseline (90.839 us; speedup 1.0000x reference)
//
#include <hip/hip_runtime.h>

// dist[b,k,n] = sqrt(max(||m||^2 + ||c||^2 - 2 c.m, 0))
// M: (B=4, D=8, N=65536) f32, centroids: (K=256, D=8) f32, out: (B,K,N) f32.
// Store-BW bound: 256 MB output. Each thread computes VEC=4 columns for a
// KCHUNK=64 slice of centroids; centroids + ||c||^2 staged in LDS (broadcast).

constexpr int B = 4;
constexpr int D = 8;
constexpr int N = 65536;
constexpr int K = 256;
constexpr int VEC = 4;
constexpr int TPB = 256;
constexpr int KCHUNK = 64;

__global__ __launch_bounds__(TPB) void ComputeDistances_82317343195698_kernel(
    const float* __restrict__ M, const float* __restrict__ C,
    float* __restrict__ out) {
  __shared__ float4 sc0[K];   // c[k][0..3]
  __shared__ float4 sc1[K];   // c[k][4..7]
  __shared__ float scsq[K];   // ||c[k]||^2

  const int tid = threadIdx.x;
  {
    // 256 threads load 256 centroid rows (2x float4 each), compute ||c||^2.
    const float4* c4 = reinterpret_cast<const float4*>(C);
    float4 a = c4[tid * 2];
    float4 b2 = c4[tid * 2 + 1];
    sc0[tid] = a;
    sc1[tid] = b2;
    scsq[tid] = a.x * a.x + a.y * a.y + a.z * a.z + a.w * a.w +
                b2.x * b2.x + b2.y * b2.y + b2.z * b2.z + b2.w * b2.w;
  }
  __syncthreads();

  const int b = blockIdx.y;
  const int n0 = (blockIdx.x * TPB + tid) * VEC;
  const int k0 = blockIdx.z * KCHUNK;

  // Load this thread's 4 columns of M: m[d][j], j = column within float4.
  float m[D][VEC];
  float msq[VEC] = {0.f, 0.f, 0.f, 0.f};
#pragma unroll
  for (int d = 0; d < D; ++d) {
    float4 v = *reinterpret_cast<const float4*>(M + ((size_t)(b * D + d) * N + n0));
    m[d][0] = v.x; m[d][1] = v.y; m[d][2] = v.z; m[d][3] = v.w;
#pragma unroll
    for (int j = 0; j < VEC; ++j) msq[j] = fmaf(m[d][j], m[d][j], msq[j]);
  }

  float* outp = out + ((size_t)(b * K + k0) * N + n0);

#pragma unroll 2
  for (int kk = 0; kk < KCHUNK; ++kk) {
    const int k = k0 + kk;
    const float4 c0 = sc0[k];   // wave-uniform -> LDS broadcast
    const float4 c1 = sc1[k];
    const float cs = scsq[k];
    float c[D] = {c0.x, c0.y, c0.z, c0.w, c1.x, c1.y, c1.z, c1.w};

    float4 r;
    float* rp = &r.x;
#pragma unroll
    for (int j = 0; j < VEC; ++j) {
      float dot = 0.f;
#pragma unroll
      for (int d = 0; d < D; ++d) dot = fmaf(c[d], m[d][j], dot);
      float d2 = fmaf(-2.f, dot, msq[j] + cs);
      rp[j] = sqrtf(fmaxf(d2, 0.f));
    }
    *reinterpret_cast<float4*>(outp + (size_t)kk * N) = r;
  }
}

extern "C" void kernel_launch(void* const* d_in, const int* in_sizes, int n_in,
                              void* d_out, int out_size, void* d_ws, size_t ws_size,
                              hipStream_t stream) {
  const float* M = (const float*)d_in[0];
  const float* C = (const float*)d_in[1];
  float* out = (float*)d_out;

  dim3 grid(N / (TPB * VEC), B, K / KCHUNK);  // (64, 4, 4) = 1024 blocks
  dim3 block(TPB);
  ComputeDistances_82317343195698_kernel<<<grid, block, 0, stream>>>(M, C, out);
}

// Round 2
// 49.371 us; speedup vs baseline: 1.8399x; 1.8399x over previous
//
#include <hip/hip_runtime.h>

// dist[b,k,n] = sqrt(max(||m||^2 + ||c||^2 - 2 c.m, 0))
// M: (B=4, D=8, N=65536) f32, centroids: (K=256, D=8) f32, out: (B,K,N) f32.
// Store-BW bound: 268 MB output. KCHUNK=16 -> 4096 blocks (full 32-wave/CU
// residency). LDS stages c2 = -2*c and ||c||^2 so inner loop is
// acc = msq + csq; 8 fma; sqrt(max). Raw v_sqrt_f32 (no fixup). Per-block
// phase stagger de-aliases the 256KB-strided store streams.

constexpr int B = 4;
constexpr int D = 8;
constexpr int N = 65536;
constexpr int K = 256;
constexpr int VEC = 4;
constexpr int TPB = 256;
constexpr int KCHUNK = 16;
constexpr int NBLK_X = N / (TPB * VEC);  // 64

__global__ __launch_bounds__(TPB) void ComputeDistances_82317343195698_kernel(
    const float* __restrict__ M, const float* __restrict__ C,
    float* __restrict__ out) {
  __shared__ float sc2[KCHUNK][D];  // -2 * c[k][d]
  __shared__ float scsq[KCHUNK];    // ||c[k]||^2

  const int tid = threadIdx.x;
  const int b = blockIdx.y;
  const int k0 = blockIdx.z * KCHUNK;

  if (tid < KCHUNK) {
    const float4* c4 = reinterpret_cast<const float4*>(C + (size_t)(k0 + tid) * D);
    float4 a = c4[0];
    float4 e = c4[1];
    scsq[tid] = a.x * a.x + a.y * a.y + a.z * a.z + a.w * a.w +
                e.x * e.x + e.y * e.y + e.z * e.z + e.w * e.w;
    sc2[tid][0] = -2.f * a.x; sc2[tid][1] = -2.f * a.y;
    sc2[tid][2] = -2.f * a.z; sc2[tid][3] = -2.f * a.w;
    sc2[tid][4] = -2.f * e.x; sc2[tid][5] = -2.f * e.y;
    sc2[tid][6] = -2.f * e.z; sc2[tid][7] = -2.f * e.w;
  }
  __syncthreads();

  const int n0 = (blockIdx.x * TPB + tid) * VEC;

  // Load this thread's 4 columns of M and their squared norms.
  float m[D][VEC];
  float msq[VEC] = {0.f, 0.f, 0.f, 0.f};
#pragma unroll
  for (int d = 0; d < D; ++d) {
    float4 v = *reinterpret_cast<const float4*>(M + ((size_t)(b * D + d) * N + n0));
    m[d][0] = v.x; m[d][1] = v.y; m[d][2] = v.z; m[d][3] = v.w;
#pragma unroll
    for (int j = 0; j < VEC; ++j) msq[j] = fmaf(m[d][j], m[d][j], msq[j]);
  }

  float* outp = out + ((size_t)(b * K + k0) * N + n0);

  // Stagger each block's k-sweep phase so concurrent stores don't all hit the
  // same offset of 256KB-aligned planes simultaneously.
  const int phase = (blockIdx.x + NBLK_X * blockIdx.y + 3 * blockIdx.z) & (KCHUNK - 1);

#pragma unroll
  for (int i = 0; i < KCHUNK; ++i) {
    const int kk = (i + phase) & (KCHUNK - 1);
    float c[D];
#pragma unroll
    for (int d = 0; d < D; ++d) c[d] = sc2[kk][d];  // wave-uniform LDS broadcast
    const float cs = scsq[kk];

    float4 r;
    float* rp = &r.x;
#pragma unroll
    for (int j = 0; j < VEC; ++j) {
      float acc = msq[j] + cs;
#pragma unroll
      for (int d = 0; d < D; ++d) acc = fmaf(c[d], m[d][j], acc);
      rp[j] = __builtin_amdgcn_sqrtf(fmaxf(acc, 0.f));
    }
    *reinterpret_cast<float4*>(outp + (size_t)kk * N) = r;
  }
}

extern "C" void kernel_launch(void* const* d_in, const int* in_sizes, int n_in,
                              void* d_out, int out_size, void* d_ws, size_t ws_size,
                              hipStream_t stream) {
  const float* M = (const float*)d_in[0];
  const float* C = (const float*)d_in[1];
  float* out = (float*)d_out;

  dim3 grid(NBLK_X, B, K / KCHUNK);  // (64, 4, 16) = 4096 blocks
  dim3 block(TPB);
  ComputeDistances_82317343195698_kernel<<<grid, block, 0, stream>>>(M, C, out);
}